// Round 4
// baseline (809.800 us; speedup 1.0000x reference)
//
#include <hip/hip_runtime.h>
#include <hip/hip_bf16.h>

#define N_NODES 100000
#define N_EDGES 1600000
#define IN_FEAT 64
#define OUT_FEAT 64
#define NUM_RELS 8

#define BSHIFT 7
#define BSZ 128                                   // nodes per bucket
#define NB ((N_NODES + BSZ - 1) / BSZ)            // 782 buckets
#define CHUNK 4096
#define NCHUNK ((N_EDGES + CHUNK - 1) / CHUNK)    // 391 edge chunks
#define PSTR 392                                  // poff row stride
#define AGG_PAD 65                                // odd-ish stride: (ld*65+lane)%32 covers all banks

// bf16 round-to-nearest-even (manual, avoids header type plumbing)
static __device__ __forceinline__ unsigned short f2bf(float x) {
    unsigned u = __float_as_uint(x);
    unsigned r = (u + 0x7FFFu + ((u >> 16) & 1u)) >> 16;
    return (unsigned short)r;
}
static __device__ __forceinline__ float bf2f(unsigned short h) {
    return __uint_as_float(((unsigned)h) << 16);
}

// ---------------------------------------------------------------------------
// K1: tr[r][n][o] (bf16) = sum_i feat[n][i] * W[r][i][o]
// Register-blocked GEMM, 4x4 micro-tile/thread (full unroll spilled at 256
// VGPR in round 1 -> 11GB scratch traffic; keep bounded unroll).
// bf16 output halves tr writes (205->102MB) and downstream gather traffic.
// ---------------------------------------------------------------------------
__global__ __launch_bounds__(256, 4) void k_transform(const float* __restrict__ feat,
                                                      const float* __restrict__ W,
                                                      unsigned short* __restrict__ trb) {
    __shared__ float Wl[64 * 64];
    __shared__ float Ft[64 * 68];
    const int tid = threadIdx.x;
    const int n0 = blockIdx.x * 64;

    #pragma unroll
    for (int it = 0; it < 4; ++it) {
        int m = it * 256 + tid;
        int n = m >> 4;
        int c4 = m & 15;
        int gn = n0 + n;
        float4 v = make_float4(0.f, 0.f, 0.f, 0.f);
        if (gn < N_NODES) v = *(const float4*)(feat + (size_t)gn * IN_FEAT + c4 * 4);
        Ft[(c4 * 4 + 0) * 68 + n] = v.x;
        Ft[(c4 * 4 + 1) * 68 + n] = v.y;
        Ft[(c4 * 4 + 2) * 68 + n] = v.z;
        Ft[(c4 * 4 + 3) * 68 + n] = v.w;
    }

    const int to = tid & 15;
    const int tn = tid >> 4;

    for (int rel = 0; rel < NUM_RELS; ++rel) {
        __syncthreads();
        {
            const float4* Wg = (const float4*)(W + (size_t)rel * 4096);
            float4* Wl4 = (float4*)Wl;
            #pragma unroll
            for (int it = 0; it < 4; ++it) Wl4[it * 256 + tid] = Wg[it * 256 + tid];
        }
        __syncthreads();

        float acc[16];
        #pragma unroll
        for (int j = 0; j < 16; ++j) acc[j] = 0.f;

        #pragma unroll 4
        for (int i = 0; i < 64; ++i) {
            float4 a = *(const float4*)(Ft + i * 68 + tn * 4);
            float4 w = *(const float4*)(Wl + i * 64 + to * 4);
            acc[0]  += a.x * w.x; acc[1]  += a.x * w.y; acc[2]  += a.x * w.z; acc[3]  += a.x * w.w;
            acc[4]  += a.y * w.x; acc[5]  += a.y * w.y; acc[6]  += a.y * w.z; acc[7]  += a.y * w.w;
            acc[8]  += a.z * w.x; acc[9]  += a.z * w.y; acc[10] += a.z * w.z; acc[11] += a.z * w.w;
            acc[12] += a.w * w.x; acc[13] += a.w * w.y; acc[14] += a.w * w.z; acc[15] += a.w * w.w;
        }

        #pragma unroll
        for (int p = 0; p < 4; ++p) {
            int gn = n0 + tn * 4 + p;
            if (gn < N_NODES) {
                ushort4 sv;
                sv.x = f2bf(acc[p * 4 + 0]);
                sv.y = f2bf(acc[p * 4 + 1]);
                sv.z = f2bf(acc[p * 4 + 2]);
                sv.w = f2bf(acc[p * 4 + 3]);
                *(ushort4*)(trb + ((size_t)rel * N_NODES + gn) * OUT_FEAT + to * 4) = sv;
            }
        }
    }
}

// ---------------------------------------------------------------------------
// Exclusive block scan over arr[0..1023] (LDS), 256 threads. Returns total.
// ---------------------------------------------------------------------------
__device__ __forceinline__ int block_scan1024(int* arr, int* tmp) {
    const int t = threadIdx.x;
    const int i0 = t * 4;
    int v0 = arr[i0], v1 = arr[i0 + 1], v2 = arr[i0 + 2], v3 = arr[i0 + 3];
    int s = v0 + v1 + v2 + v3;
    tmp[t] = s;
    __syncthreads();
    for (int off = 1; off < 256; off <<= 1) {
        int x = (t >= off) ? tmp[t - off] : 0;
        __syncthreads();
        tmp[t] += x;
        __syncthreads();
    }
    int excl = tmp[t] - s;
    int total = tmp[255];
    arr[i0]     = excl;
    arr[i0 + 1] = excl + v0;
    arr[i0 + 2] = excl + v0 + v1;
    arr[i0 + 3] = excl + v0 + v1 + v2;
    __syncthreads();
    return total;
}

// ---------------------------------------------------------------------------
// S1: per-chunk bucket histogram. cnt_kb[k][b] (coalesced writes).
// ---------------------------------------------------------------------------
__global__ __launch_bounds__(256) void k_bhist(const int* __restrict__ dst,
                                               int* __restrict__ cnt_kb) {
    __shared__ int h[NB];
    const int k = blockIdx.x, t = threadIdx.x;
    for (int i = t; i < NB; i += 256) h[i] = 0;
    __syncthreads();
    const int e0 = k * CHUNK;
    #pragma unroll
    for (int i = 0; i < 16; ++i) {
        int e = e0 + t + i * 256;
        if (e < N_EDGES) atomicAdd(&h[dst[e] >> BSHIFT], 1);
    }
    __syncthreads();
    for (int i = t; i < NB; i += 256) cnt_kb[(size_t)k * NB + i] = h[i];
}

// ---------------------------------------------------------------------------
// S2a: per-bucket prefix over chunks: poff[b][k]; bucket totals -> btot.
// ---------------------------------------------------------------------------
__global__ __launch_bounds__(256) void k_scan_bucket(const int* __restrict__ cnt_kb,
                                                     int* __restrict__ poff,
                                                     int* __restrict__ btot) {
    __shared__ int arr[1024];
    __shared__ int tmp[256];
    const int b = blockIdx.x, t = threadIdx.x;
    for (int i = t; i < 1024; i += 256)
        arr[i] = (i < NCHUNK) ? cnt_kb[(size_t)i * NB + b] : 0;
    __syncthreads();
    int total = block_scan1024(arr, tmp);
    for (int i = t; i < NCHUNK; i += 256) poff[(size_t)b * PSTR + i] = arr[i];
    if (t == 0) btot[b] = total;
}

// ---------------------------------------------------------------------------
// S2b: scan bucket totals -> bbase[0..NB], bbase[NB]=E.
// ---------------------------------------------------------------------------
__global__ __launch_bounds__(256) void k_scan_tot(const int* __restrict__ btot,
                                                  int* __restrict__ bbase) {
    __shared__ int arr[1024];
    __shared__ int tmp[256];
    const int t = threadIdx.x;
    for (int i = t; i < 1024; i += 256) arr[i] = (i < NB) ? btot[i] : 0;
    __syncthreads();
    block_scan1024(arr, tmp);
    for (int i = t; i < NB; i += 256) bbase[i] = arr[i];
    if (t == 0) bbase[NB] = N_EDGES;
}

// ---------------------------------------------------------------------------
// S3: bin edges into bucket-sorted payload with EXACT positions (no random
// 8B scatters: chunk is counting-sorted in LDS, then runs are copied to
// piecewise-contiguous global positions -> line-dense writes).
// payload = { rowid | ldst<<20 , norm bits }.
// ---------------------------------------------------------------------------
__global__ __launch_bounds__(256) void k_bin(const int* __restrict__ etypes,
                                             const int* __restrict__ src,
                                             const int* __restrict__ dst,
                                             const float* __restrict__ norm,
                                             const int* __restrict__ poff,
                                             const int* __restrict__ bbase,
                                             int2* __restrict__ payload) {
    __shared__ int hist[1024];
    __shared__ int tmp[256];
    __shared__ int lcur[NB];
    __shared__ int goff[NB];
    __shared__ int2 ordered[CHUNK];
    __shared__ unsigned short bkt_of[CHUNK];
    const int k = blockIdx.x, t = threadIdx.x;
    const int e0 = k * CHUNK;
    const int cnt = min(CHUNK, N_EDGES - e0);

    for (int i = t; i < 1024; i += 256) hist[i] = 0;
    __syncthreads();
    #pragma unroll
    for (int i = 0; i < 16; ++i) {
        int e = e0 + t + i * 256;
        if (e < N_EDGES) atomicAdd(&hist[dst[e] >> BSHIFT], 1);
    }
    __syncthreads();
    block_scan1024(hist, tmp);           // hist -> local exclusive base
    for (int i = t; i < NB; i += 256) {
        int lb = hist[i];
        lcur[i] = lb;
        goff[i] = bbase[i] + poff[(size_t)i * PSTR + k] - lb;
    }
    __syncthreads();
    #pragma unroll
    for (int i = 0; i < 16; ++i) {
        int e = e0 + t + i * 256;
        if (e < N_EDGES) {
            int d = dst[e];
            int b = d >> BSHIFT;
            int pos = atomicAdd(&lcur[b], 1);
            int rowid = etypes[e] * N_NODES + src[e];
            ordered[pos] = make_int2(rowid | ((d & (BSZ - 1)) << 20), __float_as_int(norm[e]));
            bkt_of[pos] = (unsigned short)b;
        }
    }
    __syncthreads();
    for (int j = t; j < cnt; j += 256) {
        int b = bkt_of[j];
        payload[goff[b] + j] = ordered[j];   // consecutive j -> consecutive g within a run
    }
}

// ---------------------------------------------------------------------------
// S4: block per bucket. LDS f32 accumulator [128][AGG_PAD]; whole wave per
// edge: 64 lanes read one bf16 tr row (128B coalesced), ds_add_f32 into the
// node's LDS row ((ld*65+lane)%32 covers all banks -> conflict-free). Then
// coalesced stores of the 128 node rows (zeros for degree-0 -> no memset).
// ---------------------------------------------------------------------------
__global__ __launch_bounds__(256) void k_agg(const unsigned short* __restrict__ trb,
                                             const int2* __restrict__ payload,
                                             const int* __restrict__ bbase,
                                             float* __restrict__ out) {
    __shared__ float acc[BSZ * AGG_PAD];
    const int b = blockIdx.x, t = threadIdx.x;
    const int lane = t & 63, w = t >> 6;
    for (int i = t; i < BSZ * AGG_PAD; i += 256) acc[i] = 0.f;
    __syncthreads();

    const int s0 = bbase[b], s1 = bbase[b + 1];
    int j = s0 + w;
    for (; j + 12 < s1; j += 16) {      // 4 edges in flight per wave
        int2 p0 = payload[j];
        int2 p1 = payload[j + 4];
        int2 p2 = payload[j + 8];
        int2 p3 = payload[j + 12];
        float v0 = bf2f(trb[(size_t)(p0.x & 0xFFFFF) * OUT_FEAT + lane]);
        float v1 = bf2f(trb[(size_t)(p1.x & 0xFFFFF) * OUT_FEAT + lane]);
        float v2 = bf2f(trb[(size_t)(p2.x & 0xFFFFF) * OUT_FEAT + lane]);
        float v3 = bf2f(trb[(size_t)(p3.x & 0xFFFFF) * OUT_FEAT + lane]);
        atomicAdd(&acc[((p0.x >> 20) & 127) * AGG_PAD + lane], v0 * __int_as_float(p0.y));
        atomicAdd(&acc[((p1.x >> 20) & 127) * AGG_PAD + lane], v1 * __int_as_float(p1.y));
        atomicAdd(&acc[((p2.x >> 20) & 127) * AGG_PAD + lane], v2 * __int_as_float(p2.y));
        atomicAdd(&acc[((p3.x >> 20) & 127) * AGG_PAD + lane], v3 * __int_as_float(p3.y));
    }
    for (; j < s1; j += 4) {
        int2 p = payload[j];
        float v = bf2f(trb[(size_t)(p.x & 0xFFFFF) * OUT_FEAT + lane]);
        atomicAdd(&acc[((p.x >> 20) & 127) * AGG_PAD + lane], v * __int_as_float(p.y));
    }
    __syncthreads();

    const int n0 = b << BSHIFT;
    for (int r = w; r < BSZ; r += 4) {
        int node = n0 + r;
        if (node < N_NODES) out[(size_t)node * OUT_FEAT + lane] = acc[r * AGG_PAD + lane];
    }
}

// ---------------------------------------------------------------------------
// Fallbacks for small ws.
// ---------------------------------------------------------------------------
__global__ __launch_bounds__(256) void k_scatter(const unsigned short* __restrict__ trb,
                                                 const float* __restrict__ norm,
                                                 const int* __restrict__ etypes,
                                                 const int* __restrict__ src,
                                                 const int* __restrict__ dst,
                                                 float* __restrict__ out) {
    int gid = blockIdx.x * 256 + threadIdx.x;
    int e = gid >> 4;
    int q = gid & 15;
    if (e >= N_EDGES) return;
    float nv = norm[e];
    const unsigned short* rp = trb + ((size_t)etypes[e] * N_NODES + src[e]) * OUT_FEAT + q * 4;
    ushort4 u = *(const ushort4*)rp;
    float* op = out + (size_t)dst[e] * OUT_FEAT + q * 4;
    atomicAdd(op + 0, bf2f(u.x) * nv);
    atomicAdd(op + 1, bf2f(u.y) * nv);
    atomicAdd(op + 2, bf2f(u.z) * nv);
    atomicAdd(op + 3, bf2f(u.w) * nv);
}

__global__ __launch_bounds__(256) void k_direct(const float* __restrict__ feat,
                                                const float* __restrict__ W,
                                                const float* __restrict__ norm,
                                                const int* __restrict__ etypes,
                                                const int* __restrict__ src,
                                                const int* __restrict__ dst,
                                                float* __restrict__ out) {
    int gid = blockIdx.x * 256 + threadIdx.x;
    int e = gid >> 4;
    int q = gid & 15;
    if (e >= N_EDGES) return;
    float nv = norm[e];
    const float* fs = feat + (size_t)src[e] * IN_FEAT;
    const float* wp = W + (size_t)etypes[e] * 4096 + q * 4;
    float ax = 0.f, ay = 0.f, az = 0.f, aw = 0.f;
    #pragma unroll 8
    for (int i = 0; i < IN_FEAT; ++i) {
        float f = fs[i];
        float4 w = *(const float4*)(wp + i * OUT_FEAT);
        ax += f * w.x; ay += f * w.y; az += f * w.z; aw += f * w.w;
    }
    float* op = out + (size_t)dst[e] * OUT_FEAT + q * 4;
    atomicAdd(op + 0, ax * nv);
    atomicAdd(op + 1, ay * nv);
    atomicAdd(op + 2, az * nv);
    atomicAdd(op + 3, aw * nv);
}

extern "C" void kernel_launch(void* const* d_in, const int* in_sizes, int n_in,
                              void* d_out, int out_size, void* d_ws, size_t ws_size,
                              hipStream_t stream) {
    const float* feat   = (const float*)d_in[0];
    const float* norm   = (const float*)d_in[1];
    const float* W      = (const float*)d_in[2];
    const int*   etypes = (const int*)d_in[3];
    const int*   src    = (const int*)d_in[4];
    const int*   dst    = (const int*)d_in[5];
    float* out = (float*)d_out;

    const int ntiles = (N_NODES + 63) / 64;    // 1563
    const int nscat  = (N_EDGES * 16) / 256;   // 100000

    // ws layout, 256B-aligned pieces
    const size_t sz_tr    = (size_t)NUM_RELS * N_NODES * OUT_FEAT * 2;          // 102,400,000
    const size_t sz_cnt   = (((size_t)NCHUNK * NB * 4) + 255) & ~(size_t)255;   // ~1.22 MB
    const size_t sz_poff  = (((size_t)NB * PSTR * 4) + 255) & ~(size_t)255;     // ~1.23 MB
    const size_t sz_btot  = 3328;
    const size_t sz_bbase = 3328;
    const size_t sz_pay   = (size_t)N_EDGES * 8;                                 // 12.8 MB

    char* p = (char*)d_ws;
    unsigned short* trb = (unsigned short*)p;  p += sz_tr;
    int*  cnt_kb  = (int*)p;                   p += sz_cnt;
    int*  poff    = (int*)p;                   p += sz_poff;
    int*  btot    = (int*)p;                   p += sz_btot;
    int*  bbase   = (int*)p;                   p += sz_bbase;
    int2* payload = (int2*)p;                  p += sz_pay;
    const size_t need = (size_t)(p - (char*)d_ws);   // ~117.7 MB

    if (ws_size >= need) {
        k_transform  <<<ntiles, 256, 0, stream>>>(feat, W, trb);
        k_bhist      <<<NCHUNK, 256, 0, stream>>>(dst, cnt_kb);
        k_scan_bucket<<<NB,     256, 0, stream>>>(cnt_kb, poff, btot);
        k_scan_tot   <<<1,      256, 0, stream>>>(btot, bbase);
        k_bin        <<<NCHUNK, 256, 0, stream>>>(etypes, src, dst, norm, poff, bbase, payload);
        k_agg        <<<NB,     256, 0, stream>>>(trb, payload, bbase, out);
    } else if (ws_size >= sz_tr) {
        hipMemsetAsync(d_out, 0, (size_t)out_size * sizeof(float), stream);
        k_transform<<<ntiles, 256, 0, stream>>>(feat, W, trb);
        k_scatter<<<nscat, 256, 0, stream>>>(trb, norm, etypes, src, dst, out);
    } else {
        hipMemsetAsync(d_out, 0, (size_t)out_size * sizeof(float), stream);
        k_direct<<<nscat, 256, 0, stream>>>(feat, W, norm, etypes, src, dst, out);
    }
}

// Round 5
// 803.114 us; speedup vs baseline: 1.0083x; 1.0083x over previous
//
#include <hip/hip_runtime.h>
#include <hip/hip_bf16.h>

#define N_NODES 100000
#define N_EDGES 1600000
#define IN_FEAT 64
#define OUT_FEAT 64
#define NUM_RELS 8

#define BSHIFT 7
#define BSZ 128                                   // nodes per bucket
#define NB ((N_NODES + BSZ - 1) / BSZ)            // 782 buckets
#define CHUNK 4096
#define NCHUNK ((N_EDGES + CHUNK - 1) / CHUNK)    // 391 edge chunks
#define PSTR 392                                  // poff row stride
#define AGG_PAD 65                                // (r*65+q*4+k)%32 = (r+4q+k)%32: 2-way max per group
#define PTILE 2048                                // payload LDS tile (16KB)

// bf16 round-to-nearest-even (manual, avoids header type plumbing)
static __device__ __forceinline__ unsigned short f2bf(float x) {
    unsigned u = __float_as_uint(x);
    unsigned r = (u + 0x7FFFu + ((u >> 16) & 1u)) >> 16;
    return (unsigned short)r;
}
static __device__ __forceinline__ float bf2f(unsigned short h) {
    return __uint_as_float(((unsigned)h) << 16);
}

// ---------------------------------------------------------------------------
// K1: tr[r][n][o] (bf16) = sum_i feat[n][i] * W[r][i][o]
// Register-blocked GEMM, 4x4 micro-tile/thread (full unroll spilled at 256
// VGPR in round 1 -> 11GB scratch traffic; keep bounded unroll).
// ---------------------------------------------------------------------------
__global__ __launch_bounds__(256, 4) void k_transform(const float* __restrict__ feat,
                                                      const float* __restrict__ W,
                                                      unsigned short* __restrict__ trb) {
    __shared__ float Wl[64 * 64];
    __shared__ float Ft[64 * 68];
    const int tid = threadIdx.x;
    const int n0 = blockIdx.x * 64;

    #pragma unroll
    for (int it = 0; it < 4; ++it) {
        int m = it * 256 + tid;
        int n = m >> 4;
        int c4 = m & 15;
        int gn = n0 + n;
        float4 v = make_float4(0.f, 0.f, 0.f, 0.f);
        if (gn < N_NODES) v = *(const float4*)(feat + (size_t)gn * IN_FEAT + c4 * 4);
        Ft[(c4 * 4 + 0) * 68 + n] = v.x;
        Ft[(c4 * 4 + 1) * 68 + n] = v.y;
        Ft[(c4 * 4 + 2) * 68 + n] = v.z;
        Ft[(c4 * 4 + 3) * 68 + n] = v.w;
    }

    const int to = tid & 15;
    const int tn = tid >> 4;

    for (int rel = 0; rel < NUM_RELS; ++rel) {
        __syncthreads();
        {
            const float4* Wg = (const float4*)(W + (size_t)rel * 4096);
            float4* Wl4 = (float4*)Wl;
            #pragma unroll
            for (int it = 0; it < 4; ++it) Wl4[it * 256 + tid] = Wg[it * 256 + tid];
        }
        __syncthreads();

        float acc[16];
        #pragma unroll
        for (int j = 0; j < 16; ++j) acc[j] = 0.f;

        #pragma unroll 4
        for (int i = 0; i < 64; ++i) {
            float4 a = *(const float4*)(Ft + i * 68 + tn * 4);
            float4 w = *(const float4*)(Wl + i * 64 + to * 4);
            acc[0]  += a.x * w.x; acc[1]  += a.x * w.y; acc[2]  += a.x * w.z; acc[3]  += a.x * w.w;
            acc[4]  += a.y * w.x; acc[5]  += a.y * w.y; acc[6]  += a.y * w.z; acc[7]  += a.y * w.w;
            acc[8]  += a.z * w.x; acc[9]  += a.z * w.y; acc[10] += a.z * w.z; acc[11] += a.z * w.w;
            acc[12] += a.w * w.x; acc[13] += a.w * w.y; acc[14] += a.w * w.z; acc[15] += a.w * w.w;
        }

        #pragma unroll
        for (int p = 0; p < 4; ++p) {
            int gn = n0 + tn * 4 + p;
            if (gn < N_NODES) {
                ushort4 sv;
                sv.x = f2bf(acc[p * 4 + 0]);
                sv.y = f2bf(acc[p * 4 + 1]);
                sv.z = f2bf(acc[p * 4 + 2]);
                sv.w = f2bf(acc[p * 4 + 3]);
                *(ushort4*)(trb + ((size_t)rel * N_NODES + gn) * OUT_FEAT + to * 4) = sv;
            }
        }
    }
}

// ---------------------------------------------------------------------------
// Exclusive block scan over arr[0..1023] (LDS), 256 threads. Returns total.
// ---------------------------------------------------------------------------
__device__ __forceinline__ int block_scan1024(int* arr, int* tmp) {
    const int t = threadIdx.x;
    const int i0 = t * 4;
    int v0 = arr[i0], v1 = arr[i0 + 1], v2 = arr[i0 + 2], v3 = arr[i0 + 3];
    int s = v0 + v1 + v2 + v3;
    tmp[t] = s;
    __syncthreads();
    for (int off = 1; off < 256; off <<= 1) {
        int x = (t >= off) ? tmp[t - off] : 0;
        __syncthreads();
        tmp[t] += x;
        __syncthreads();
    }
    int excl = tmp[t] - s;
    int total = tmp[255];
    arr[i0]     = excl;
    arr[i0 + 1] = excl + v0;
    arr[i0 + 2] = excl + v0 + v1;
    arr[i0 + 3] = excl + v0 + v1 + v2;
    __syncthreads();
    return total;
}

// ---------------------------------------------------------------------------
// S1: per-chunk bucket histogram. cnt_kb[k][b] (coalesced writes).
// ---------------------------------------------------------------------------
__global__ __launch_bounds__(256) void k_bhist(const int* __restrict__ dst,
                                               int* __restrict__ cnt_kb) {
    __shared__ int h[NB];
    const int k = blockIdx.x, t = threadIdx.x;
    for (int i = t; i < NB; i += 256) h[i] = 0;
    __syncthreads();
    const int e0 = k * CHUNK;
    #pragma unroll
    for (int i = 0; i < 16; ++i) {
        int e = e0 + t + i * 256;
        if (e < N_EDGES) atomicAdd(&h[dst[e] >> BSHIFT], 1);
    }
    __syncthreads();
    for (int i = t; i < NB; i += 256) cnt_kb[(size_t)k * NB + i] = h[i];
}

// ---------------------------------------------------------------------------
// S2a: per-bucket prefix over chunks: poff[b][k]; bucket totals -> btot.
// ---------------------------------------------------------------------------
__global__ __launch_bounds__(256) void k_scan_bucket(const int* __restrict__ cnt_kb,
                                                     int* __restrict__ poff,
                                                     int* __restrict__ btot) {
    __shared__ int arr[1024];
    __shared__ int tmp[256];
    const int b = blockIdx.x, t = threadIdx.x;
    for (int i = t; i < 1024; i += 256)
        arr[i] = (i < NCHUNK) ? cnt_kb[(size_t)i * NB + b] : 0;
    __syncthreads();
    int total = block_scan1024(arr, tmp);
    for (int i = t; i < NCHUNK; i += 256) poff[(size_t)b * PSTR + i] = arr[i];
    if (t == 0) btot[b] = total;
}

// ---------------------------------------------------------------------------
// S2b: scan bucket totals -> bbase[0..NB], bbase[NB]=E.
// ---------------------------------------------------------------------------
__global__ __launch_bounds__(256) void k_scan_tot(const int* __restrict__ btot,
                                                  int* __restrict__ bbase) {
    __shared__ int arr[1024];
    __shared__ int tmp[256];
    const int t = threadIdx.x;
    for (int i = t; i < 1024; i += 256) arr[i] = (i < NB) ? btot[i] : 0;
    __syncthreads();
    block_scan1024(arr, tmp);
    for (int i = t; i < NB; i += 256) bbase[i] = arr[i];
    if (t == 0) bbase[NB] = N_EDGES;
}

// ---------------------------------------------------------------------------
// S3: bin edges into bucket-sorted payload with EXACT positions (chunk is
// counting-sorted in LDS, runs copied to piecewise-contiguous global
// positions -> line-dense writes). payload = { rowid | ldst<<20 , norm }.
// ---------------------------------------------------------------------------
__global__ __launch_bounds__(256) void k_bin(const int* __restrict__ etypes,
                                             const int* __restrict__ src,
                                             const int* __restrict__ dst,
                                             const float* __restrict__ norm,
                                             const int* __restrict__ poff,
                                             const int* __restrict__ bbase,
                                             int2* __restrict__ payload) {
    __shared__ int hist[1024];
    __shared__ int tmp[256];
    __shared__ int lcur[NB];
    __shared__ int goff[NB];
    __shared__ int2 ordered[CHUNK];
    __shared__ unsigned short bkt_of[CHUNK];
    const int k = blockIdx.x, t = threadIdx.x;
    const int e0 = k * CHUNK;
    const int cnt = min(CHUNK, N_EDGES - e0);

    for (int i = t; i < 1024; i += 256) hist[i] = 0;
    __syncthreads();
    #pragma unroll
    for (int i = 0; i < 16; ++i) {
        int e = e0 + t + i * 256;
        if (e < N_EDGES) atomicAdd(&hist[dst[e] >> BSHIFT], 1);
    }
    __syncthreads();
    block_scan1024(hist, tmp);           // hist -> local exclusive base
    for (int i = t; i < NB; i += 256) {
        int lb = hist[i];
        lcur[i] = lb;
        goff[i] = bbase[i] + poff[(size_t)i * PSTR + k] - lb;
    }
    __syncthreads();
    #pragma unroll
    for (int i = 0; i < 16; ++i) {
        int e = e0 + t + i * 256;
        if (e < N_EDGES) {
            int d = dst[e];
            int b = d >> BSHIFT;
            int pos = atomicAdd(&lcur[b], 1);
            int rowid = etypes[e] * N_NODES + src[e];
            ordered[pos] = make_int2(rowid | ((d & (BSZ - 1)) << 20), __float_as_int(norm[e]));
            bkt_of[pos] = (unsigned short)b;
        }
    }
    __syncthreads();
    for (int j = t; j < cnt; j += 256) {
        int b = bkt_of[j];
        payload[goff[b] + j] = ordered[j];   // consecutive j -> consecutive g within a run
    }
}

// ---------------------------------------------------------------------------
// S4: block (512 thr = 8 waves) per bucket. Round-4 version was latency-bound
// (12 waves/CU, serial payload->gather chain, 150GB/s): fix = stage payload
// tile in LDS (coalesced, breaks dependent chain), 16-lane groups so each
// wave has 4 concurrent row-gathers x2 unroll, 24 waves/CU -> ~8x MLP.
// ---------------------------------------------------------------------------
__global__ __launch_bounds__(512) void k_agg(const unsigned short* __restrict__ trb,
                                             const int2* __restrict__ payload,
                                             const int* __restrict__ bbase,
                                             float* __restrict__ out) {
    __shared__ float acc[BSZ * AGG_PAD];   // 33,280 B
    __shared__ int2 pseg[PTILE];           // 16,384 B
    const int b = blockIdx.x, t = threadIdx.x;
    const int lane = t & 63, w = t >> 6;   // wave 0..7
    const int g = lane >> 4, q = lane & 15;

    for (int i = t; i < BSZ * AGG_PAD; i += 512) acc[i] = 0.f;

    const int s0 = bbase[b], s1 = bbase[b + 1];

    for (int jb = s0; jb < s1; jb += PTILE) {
        const int cnt = min(PTILE, s1 - jb);
        __syncthreads();   // previous tile fully consumed (and acc init on first pass)
        for (int i = t; i < cnt; i += 512) pseg[i] = payload[jb + i];
        __syncthreads();

        int i = w * 4 + g;                 // 8 waves x 4 groups = 32 edges per sweep
        for (; i + 32 < cnt; i += 64) {
            int2 pa = pseg[i];
            int2 pb = pseg[i + 32];
            ushort4 ua = *(const ushort4*)(trb + (size_t)(pa.x & 0xFFFFF) * OUT_FEAT + q * 4);
            ushort4 ub = *(const ushort4*)(trb + (size_t)(pb.x & 0xFFFFF) * OUT_FEAT + q * 4);
            float na = __int_as_float(pa.y), nb_ = __int_as_float(pb.y);
            float* ra = &acc[((pa.x >> 20) & 127) * AGG_PAD + q * 4];
            float* rb = &acc[((pb.x >> 20) & 127) * AGG_PAD + q * 4];
            atomicAdd(ra + 0, bf2f(ua.x) * na);
            atomicAdd(ra + 1, bf2f(ua.y) * na);
            atomicAdd(ra + 2, bf2f(ua.z) * na);
            atomicAdd(ra + 3, bf2f(ua.w) * na);
            atomicAdd(rb + 0, bf2f(ub.x) * nb_);
            atomicAdd(rb + 1, bf2f(ub.y) * nb_);
            atomicAdd(rb + 2, bf2f(ub.z) * nb_);
            atomicAdd(rb + 3, bf2f(ub.w) * nb_);
        }
        if (i < cnt) {
            int2 p = pseg[i];
            ushort4 u = *(const ushort4*)(trb + (size_t)(p.x & 0xFFFFF) * OUT_FEAT + q * 4);
            float nv = __int_as_float(p.y);
            float* r = &acc[((p.x >> 20) & 127) * AGG_PAD + q * 4];
            atomicAdd(r + 0, bf2f(u.x) * nv);
            atomicAdd(r + 1, bf2f(u.y) * nv);
            atomicAdd(r + 2, bf2f(u.z) * nv);
            atomicAdd(r + 3, bf2f(u.w) * nv);
        }
    }
    __syncthreads();

    const int n0 = b << BSHIFT;
    for (int r = w; r < BSZ; r += 8) {
        int node = n0 + r;
        if (node < N_NODES) out[(size_t)node * OUT_FEAT + lane] = acc[r * AGG_PAD + lane];
    }
}

// ---------------------------------------------------------------------------
// Fallbacks for small ws.
// ---------------------------------------------------------------------------
__global__ __launch_bounds__(256) void k_scatter(const unsigned short* __restrict__ trb,
                                                 const float* __restrict__ norm,
                                                 const int* __restrict__ etypes,
                                                 const int* __restrict__ src,
                                                 const int* __restrict__ dst,
                                                 float* __restrict__ out) {
    int gid = blockIdx.x * 256 + threadIdx.x;
    int e = gid >> 4;
    int q = gid & 15;
    if (e >= N_EDGES) return;
    float nv = norm[e];
    const unsigned short* rp = trb + ((size_t)etypes[e] * N_NODES + src[e]) * OUT_FEAT + q * 4;
    ushort4 u = *(const ushort4*)rp;
    float* op = out + (size_t)dst[e] * OUT_FEAT + q * 4;
    atomicAdd(op + 0, bf2f(u.x) * nv);
    atomicAdd(op + 1, bf2f(u.y) * nv);
    atomicAdd(op + 2, bf2f(u.z) * nv);
    atomicAdd(op + 3, bf2f(u.w) * nv);
}

__global__ __launch_bounds__(256) void k_direct(const float* __restrict__ feat,
                                                const float* __restrict__ W,
                                                const float* __restrict__ norm,
                                                const int* __restrict__ etypes,
                                                const int* __restrict__ src,
                                                const int* __restrict__ dst,
                                                float* __restrict__ out) {
    int gid = blockIdx.x * 256 + threadIdx.x;
    int e = gid >> 4;
    int q = gid & 15;
    if (e >= N_EDGES) return;
    float nv = norm[e];
    const float* fs = feat + (size_t)src[e] * IN_FEAT;
    const float* wp = W + (size_t)etypes[e] * 4096 + q * 4;
    float ax = 0.f, ay = 0.f, az = 0.f, aw = 0.f;
    #pragma unroll 8
    for (int i = 0; i < IN_FEAT; ++i) {
        float f = fs[i];
        float4 w = *(const float4*)(wp + i * OUT_FEAT);
        ax += f * w.x; ay += f * w.y; az += f * w.z; aw += f * w.w;
    }
    float* op = out + (size_t)dst[e] * OUT_FEAT + q * 4;
    atomicAdd(op + 0, ax * nv);
    atomicAdd(op + 1, ay * nv);
    atomicAdd(op + 2, az * nv);
    atomicAdd(op + 3, aw * nv);
}

extern "C" void kernel_launch(void* const* d_in, const int* in_sizes, int n_in,
                              void* d_out, int out_size, void* d_ws, size_t ws_size,
                              hipStream_t stream) {
    const float* feat   = (const float*)d_in[0];
    const float* norm   = (const float*)d_in[1];
    const float* W      = (const float*)d_in[2];
    const int*   etypes = (const int*)d_in[3];
    const int*   src    = (const int*)d_in[4];
    const int*   dst    = (const int*)d_in[5];
    float* out = (float*)d_out;

    const int ntiles = (N_NODES + 63) / 64;    // 1563
    const int nscat  = (N_EDGES * 16) / 256;   // 100000

    // ws layout, 256B-aligned pieces
    const size_t sz_tr    = (size_t)NUM_RELS * N_NODES * OUT_FEAT * 2;          // 102,400,000
    const size_t sz_cnt   = (((size_t)NCHUNK * NB * 4) + 255) & ~(size_t)255;   // ~1.22 MB
    const size_t sz_poff  = (((size_t)NB * PSTR * 4) + 255) & ~(size_t)255;     // ~1.23 MB
    const size_t sz_btot  = 3328;
    const size_t sz_bbase = 3328;
    const size_t sz_pay   = (size_t)N_EDGES * 8;                                 // 12.8 MB

    char* p = (char*)d_ws;
    unsigned short* trb = (unsigned short*)p;  p += sz_tr;
    int*  cnt_kb  = (int*)p;                   p += sz_cnt;
    int*  poff    = (int*)p;                   p += sz_poff;
    int*  btot    = (int*)p;                   p += sz_btot;
    int*  bbase   = (int*)p;                   p += sz_bbase;
    int2* payload = (int2*)p;                  p += sz_pay;
    const size_t need = (size_t)(p - (char*)d_ws);   // ~117.7 MB

    if (ws_size >= need) {
        k_transform  <<<ntiles, 256, 0, stream>>>(feat, W, trb);
        k_bhist      <<<NCHUNK, 256, 0, stream>>>(dst, cnt_kb);
        k_scan_bucket<<<NB,     256, 0, stream>>>(cnt_kb, poff, btot);
        k_scan_tot   <<<1,      256, 0, stream>>>(btot, bbase);
        k_bin        <<<NCHUNK, 256, 0, stream>>>(etypes, src, dst, norm, poff, bbase, payload);
        k_agg        <<<NB,     512, 0, stream>>>(trb, payload, bbase, out);
    } else if (ws_size >= sz_tr) {
        hipMemsetAsync(d_out, 0, (size_t)out_size * sizeof(float), stream);
        k_transform<<<ntiles, 256, 0, stream>>>(feat, W, trb);
        k_scatter<<<nscat, 256, 0, stream>>>(trb, norm, etypes, src, dst, out);
    } else {
        hipMemsetAsync(d_out, 0, (size_t)out_size * sizeof(float), stream);
        k_direct<<<nscat, 256, 0, stream>>>(feat, W, norm, etypes, src, dst, out);
    }
}

// Round 6
// 180.444 us; speedup vs baseline: 4.4878x; 4.4508x over previous
//
#include <hip/hip_runtime.h>
#include <hip/hip_bf16.h>

#define N_NODES 100000
#define N_EDGES 1600000
#define IN_FEAT 64
#define OUT_FEAT 64
#define NUM_RELS 8

#define BSHIFT 7
#define BSZ 128                                   // nodes per bucket
#define NB ((N_NODES + BSZ - 1) / BSZ)            // 782 buckets
#define CHUNK 4096
#define NCHUNK ((N_EDGES + CHUNK - 1) / CHUNK)    // 391 edge chunks
#define PSTR 392                                  // poff row stride
#define MAXBUCK 2944                              // bucket LDS cap (mean 2046, ~20 sigma)

// bf16 helpers
static __device__ __forceinline__ unsigned short f2bf(float x) {
    unsigned u = __float_as_uint(x);
    unsigned r = (u + 0x7FFFu + ((u >> 16) & 1u)) >> 16;
    return (unsigned short)r;
}
static __device__ __forceinline__ float bf2f(unsigned short h) {
    return __uint_as_float(((unsigned)h) << 16);
}
static __device__ __forceinline__ float bflo(unsigned v) { return __uint_as_float(v << 16); }
static __device__ __forceinline__ float bfhi(unsigned v) { return __uint_as_float(v & 0xFFFF0000u); }

// ---------------------------------------------------------------------------
// K1: tr[r][n][o] (bf16) = sum_i feat[n][i] * W[r][i][o]
// Register-blocked GEMM, 4x4 micro-tile/thread (full unroll spilled at 256
// VGPR in round 1 -> 11GB scratch traffic; keep bounded unroll).
// ---------------------------------------------------------------------------
__global__ __launch_bounds__(256, 4) void k_transform(const float* __restrict__ feat,
                                                      const float* __restrict__ W,
                                                      unsigned short* __restrict__ trb) {
    __shared__ float Wl[64 * 64];
    __shared__ float Ft[64 * 68];
    const int tid = threadIdx.x;
    const int n0 = blockIdx.x * 64;

    #pragma unroll
    for (int it = 0; it < 4; ++it) {
        int m = it * 256 + tid;
        int n = m >> 4;
        int c4 = m & 15;
        int gn = n0 + n;
        float4 v = make_float4(0.f, 0.f, 0.f, 0.f);
        if (gn < N_NODES) v = *(const float4*)(feat + (size_t)gn * IN_FEAT + c4 * 4);
        Ft[(c4 * 4 + 0) * 68 + n] = v.x;
        Ft[(c4 * 4 + 1) * 68 + n] = v.y;
        Ft[(c4 * 4 + 2) * 68 + n] = v.z;
        Ft[(c4 * 4 + 3) * 68 + n] = v.w;
    }

    const int to = tid & 15;
    const int tn = tid >> 4;

    for (int rel = 0; rel < NUM_RELS; ++rel) {
        __syncthreads();
        {
            const float4* Wg = (const float4*)(W + (size_t)rel * 4096);
            float4* Wl4 = (float4*)Wl;
            #pragma unroll
            for (int it = 0; it < 4; ++it) Wl4[it * 256 + tid] = Wg[it * 256 + tid];
        }
        __syncthreads();

        float acc[16];
        #pragma unroll
        for (int j = 0; j < 16; ++j) acc[j] = 0.f;

        #pragma unroll 4
        for (int i = 0; i < 64; ++i) {
            float4 a = *(const float4*)(Ft + i * 68 + tn * 4);
            float4 w = *(const float4*)(Wl + i * 64 + to * 4);
            acc[0]  += a.x * w.x; acc[1]  += a.x * w.y; acc[2]  += a.x * w.z; acc[3]  += a.x * w.w;
            acc[4]  += a.y * w.x; acc[5]  += a.y * w.y; acc[6]  += a.y * w.z; acc[7]  += a.y * w.w;
            acc[8]  += a.z * w.x; acc[9]  += a.z * w.y; acc[10] += a.z * w.z; acc[11] += a.z * w.w;
            acc[12] += a.w * w.x; acc[13] += a.w * w.y; acc[14] += a.w * w.z; acc[15] += a.w * w.w;
        }

        #pragma unroll
        for (int p = 0; p < 4; ++p) {
            int gn = n0 + tn * 4 + p;
            if (gn < N_NODES) {
                ushort4 sv;
                sv.x = f2bf(acc[p * 4 + 0]);
                sv.y = f2bf(acc[p * 4 + 1]);
                sv.z = f2bf(acc[p * 4 + 2]);
                sv.w = f2bf(acc[p * 4 + 3]);
                *(ushort4*)(trb + ((size_t)rel * N_NODES + gn) * OUT_FEAT + to * 4) = sv;
            }
        }
    }
}

// ---------------------------------------------------------------------------
// Exclusive block scan over arr[0..1023] (LDS), 256 threads. Returns total.
// ---------------------------------------------------------------------------
__device__ __forceinline__ int block_scan1024(int* arr, int* tmp) {
    const int t = threadIdx.x;
    const int i0 = t * 4;
    int v0 = arr[i0], v1 = arr[i0 + 1], v2 = arr[i0 + 2], v3 = arr[i0 + 3];
    int s = v0 + v1 + v2 + v3;
    tmp[t] = s;
    __syncthreads();
    for (int off = 1; off < 256; off <<= 1) {
        int x = (t >= off) ? tmp[t - off] : 0;
        __syncthreads();
        tmp[t] += x;
        __syncthreads();
    }
    int excl = tmp[t] - s;
    int total = tmp[255];
    arr[i0]     = excl;
    arr[i0 + 1] = excl + v0;
    arr[i0 + 2] = excl + v0 + v1;
    arr[i0 + 3] = excl + v0 + v1 + v2;
    __syncthreads();
    return total;
}

// ---------------------------------------------------------------------------
// S1: per-chunk bucket histogram. cnt_kb[k][b] (coalesced writes).
// ---------------------------------------------------------------------------
__global__ __launch_bounds__(256) void k_bhist(const int* __restrict__ dst,
                                               int* __restrict__ cnt_kb) {
    __shared__ int h[NB];
    const int k = blockIdx.x, t = threadIdx.x;
    for (int i = t; i < NB; i += 256) h[i] = 0;
    __syncthreads();
    const int e0 = k * CHUNK;
    #pragma unroll
    for (int i = 0; i < 16; ++i) {
        int e = e0 + t + i * 256;
        if (e < N_EDGES) atomicAdd(&h[dst[e] >> BSHIFT], 1);
    }
    __syncthreads();
    for (int i = t; i < NB; i += 256) cnt_kb[(size_t)k * NB + i] = h[i];
}

// ---------------------------------------------------------------------------
// S2a: per-bucket prefix over chunks: poff[b][k]; bucket totals -> btot.
// ---------------------------------------------------------------------------
__global__ __launch_bounds__(256) void k_scan_bucket(const int* __restrict__ cnt_kb,
                                                     int* __restrict__ poff,
                                                     int* __restrict__ btot) {
    __shared__ int arr[1024];
    __shared__ int tmp[256];
    const int b = blockIdx.x, t = threadIdx.x;
    for (int i = t; i < 1024; i += 256)
        arr[i] = (i < NCHUNK) ? cnt_kb[(size_t)i * NB + b] : 0;
    __syncthreads();
    int total = block_scan1024(arr, tmp);
    for (int i = t; i < NCHUNK; i += 256) poff[(size_t)b * PSTR + i] = arr[i];
    if (t == 0) btot[b] = total;
}

// ---------------------------------------------------------------------------
// S2b: scan bucket totals -> bbase[0..NB], bbase[NB]=E.
// ---------------------------------------------------------------------------
__global__ __launch_bounds__(256) void k_scan_tot(const int* __restrict__ btot,
                                                  int* __restrict__ bbase) {
    __shared__ int arr[1024];
    __shared__ int tmp[256];
    const int t = threadIdx.x;
    for (int i = t; i < 1024; i += 256) arr[i] = (i < NB) ? btot[i] : 0;
    __syncthreads();
    block_scan1024(arr, tmp);
    for (int i = t; i < NB; i += 256) bbase[i] = arr[i];
    if (t == 0) bbase[NB] = N_EDGES;
}

// ---------------------------------------------------------------------------
// S3: bin edges into bucket-sorted payload with EXACT positions (chunk is
// counting-sorted in LDS, runs copied to piecewise-contiguous global
// positions -> line-dense writes). payload = { rowid | ldst<<20 , norm }.
// ---------------------------------------------------------------------------
__global__ __launch_bounds__(256) void k_bin(const int* __restrict__ etypes,
                                             const int* __restrict__ src,
                                             const int* __restrict__ dst,
                                             const float* __restrict__ norm,
                                             const int* __restrict__ poff,
                                             const int* __restrict__ bbase,
                                             int2* __restrict__ payload) {
    __shared__ int hist[1024];
    __shared__ int tmp[256];
    __shared__ int lcur[NB];
    __shared__ int goff[NB];
    __shared__ int2 ordered[CHUNK];
    __shared__ unsigned short bkt_of[CHUNK];
    const int k = blockIdx.x, t = threadIdx.x;
    const int e0 = k * CHUNK;
    const int cnt = min(CHUNK, N_EDGES - e0);

    for (int i = t; i < 1024; i += 256) hist[i] = 0;
    __syncthreads();
    #pragma unroll
    for (int i = 0; i < 16; ++i) {
        int e = e0 + t + i * 256;
        if (e < N_EDGES) atomicAdd(&hist[dst[e] >> BSHIFT], 1);
    }
    __syncthreads();
    block_scan1024(hist, tmp);           // hist -> local exclusive base
    for (int i = t; i < NB; i += 256) {
        int lb = hist[i];
        lcur[i] = lb;
        goff[i] = bbase[i] + poff[(size_t)i * PSTR + k] - lb;
    }
    __syncthreads();
    #pragma unroll
    for (int i = 0; i < 16; ++i) {
        int e = e0 + t + i * 256;
        if (e < N_EDGES) {
            int d = dst[e];
            int b = d >> BSHIFT;
            int pos = atomicAdd(&lcur[b], 1);
            int rowid = etypes[e] * N_NODES + src[e];
            ordered[pos] = make_int2(rowid | ((d & (BSZ - 1)) << 20), __float_as_int(norm[e]));
            bkt_of[pos] = (unsigned short)b;
        }
    }
    __syncthreads();
    for (int j = t; j < cnt; j += 256) {
        int b = bkt_of[j];
        payload[goff[b] + j] = ordered[j];   // consecutive j -> consecutive g within a run
    }
}

// ---------------------------------------------------------------------------
// S4 v3: block (512 thr) per bucket. Rounds 4/5 both hit the same 680us wall
// with per-edge LDS-atomic accumulation (two different MLP structures, same
// time) -> eliminate atomics entirely. Stage bucket payload in LDS, counting-
// sort by node (128 counters + scan + ushort perm), then 64 8-lane groups
// each own 2 nodes: gather bf16 rows (uint4/lane), accumulate in 8 f32
// REGISTERS, one direct row store per node (zeros for degree-0).
// ---------------------------------------------------------------------------
__global__ __launch_bounds__(512) void k_agg(const unsigned short* __restrict__ trb,
                                             const int2* __restrict__ payload,
                                             const int* __restrict__ bbase,
                                             float* __restrict__ out) {
    __shared__ int2 pseg[MAXBUCK];            // 23,552 B
    __shared__ unsigned short sidx[MAXBUCK];  //  5,888 B
    __shared__ int cnt128[BSZ];
    __shared__ int scan_tmp[BSZ];
    __shared__ int ncur[BSZ];
    __shared__ int nbase[BSZ + 1];
    const int b = blockIdx.x, t = threadIdx.x;

    const int s0 = bbase[b], s1 = bbase[b + 1];
    const int cntb = s1 - s0;
    const int cstage = min(cntb, MAXBUCK);

    if (t < BSZ) cnt128[t] = 0;
    __syncthreads();

    // stage + histogram (coalesced int2 loads)
    for (int i = t; i < cstage; i += 512) {
        int2 p = payload[s0 + i];
        pseg[i] = p;
        atomicAdd(&cnt128[(p.x >> 20) & 127], 1);
    }
    __syncthreads();

    // exclusive scan of 128 node counters (first 128 threads, full-block syncs)
    if (t < BSZ) scan_tmp[t] = cnt128[t];
    __syncthreads();
    for (int off = 1; off < BSZ; off <<= 1) {
        int x = 0;
        if (t < BSZ && t >= off) x = scan_tmp[t - off];
        __syncthreads();
        if (t < BSZ) scan_tmp[t] += x;
        __syncthreads();
    }
    if (t < BSZ) {
        int inc = scan_tmp[t];
        int exc = inc - cnt128[t];
        nbase[t] = exc;
        ncur[t] = exc;
        if (t == BSZ - 1) nbase[BSZ] = inc;
    }
    __syncthreads();

    // scatter permutation indices (node-sorted order)
    for (int i = t; i < cstage; i += 512) {
        int ld = (pseg[i].x >> 20) & 127;
        int pos = atomicAdd(&ncur[ld], 1);
        sidx[pos] = (unsigned short)i;
    }
    __syncthreads();

    // phase 2: 64 groups of 8 lanes; each group owns nodes gg and gg+64
    const int gg = t >> 3;          // group id 0..63
    const int q  = t & 7;           // lane within group
    const int n0g = b << BSHIFT;

    #pragma unroll
    for (int rr = 0; rr < 2; ++rr) {
        int r = gg + rr * 64;
        int j0 = nbase[r], j1 = nbase[r + 1];
        float a0 = 0.f, a1 = 0.f, a2 = 0.f, a3 = 0.f;
        float a4 = 0.f, a5 = 0.f, a6 = 0.f, a7 = 0.f;
        int j = j0;
        for (; j + 1 < j1; j += 2) {
            int2 pa = pseg[sidx[j]];
            int2 pb = pseg[sidx[j + 1]];
            uint4 ua = *(const uint4*)(trb + (size_t)(pa.x & 0xFFFFF) * OUT_FEAT + (q << 3));
            uint4 ub = *(const uint4*)(trb + (size_t)(pb.x & 0xFFFFF) * OUT_FEAT + (q << 3));
            float na = __int_as_float(pa.y);
            float nb_ = __int_as_float(pb.y);
            a0 += bflo(ua.x) * na; a1 += bfhi(ua.x) * na;
            a2 += bflo(ua.y) * na; a3 += bfhi(ua.y) * na;
            a4 += bflo(ua.z) * na; a5 += bfhi(ua.z) * na;
            a6 += bflo(ua.w) * na; a7 += bfhi(ua.w) * na;
            a0 += bflo(ub.x) * nb_; a1 += bfhi(ub.x) * nb_;
            a2 += bflo(ub.y) * nb_; a3 += bfhi(ub.y) * nb_;
            a4 += bflo(ub.z) * nb_; a5 += bfhi(ub.z) * nb_;
            a6 += bflo(ub.w) * nb_; a7 += bfhi(ub.w) * nb_;
        }
        if (j < j1) {
            int2 p = pseg[sidx[j]];
            uint4 u = *(const uint4*)(trb + (size_t)(p.x & 0xFFFFF) * OUT_FEAT + (q << 3));
            float nv = __int_as_float(p.y);
            a0 += bflo(u.x) * nv; a1 += bfhi(u.x) * nv;
            a2 += bflo(u.y) * nv; a3 += bfhi(u.y) * nv;
            a4 += bflo(u.z) * nv; a5 += bfhi(u.z) * nv;
            a6 += bflo(u.w) * nv; a7 += bfhi(u.w) * nv;
        }
        int n = n0g + r;
        if (n < N_NODES) {
            float* op = out + (size_t)n * OUT_FEAT + (q << 3);
            *(float4*)op       = make_float4(a0, a1, a2, a3);
            *(float4*)(op + 4) = make_float4(a4, a5, a6, a7);
        }
    }

    // overflow fallback (cntb > MAXBUCK): never taken for this input (~20
    // sigma margin), kept for correctness. Runs after this block's stores.
    if (cntb > MAXBUCK) {
        __syncthreads();
        for (int i = MAXBUCK + t; i < cntb; i += 512) {
            int2 p = payload[s0 + i];
            int row = p.x & 0xFFFFF;
            int n = n0g + ((p.x >> 20) & 127);
            float nv = __int_as_float(p.y);
            if (n < N_NODES)
                for (int c = 0; c < OUT_FEAT; ++c)
                    atomicAdd(&out[(size_t)n * OUT_FEAT + c],
                              bf2f(trb[(size_t)row * OUT_FEAT + c]) * nv);
        }
    }
}

// ---------------------------------------------------------------------------
// Fallbacks for small ws.
// ---------------------------------------------------------------------------
__global__ __launch_bounds__(256) void k_scatter(const unsigned short* __restrict__ trb,
                                                 const float* __restrict__ norm,
                                                 const int* __restrict__ etypes,
                                                 const int* __restrict__ src,
                                                 const int* __restrict__ dst,
                                                 float* __restrict__ out) {
    int gid = blockIdx.x * 256 + threadIdx.x;
    int e = gid >> 4;
    int q = gid & 15;
    if (e >= N_EDGES) return;
    float nv = norm[e];
    const unsigned short* rp = trb + ((size_t)etypes[e] * N_NODES + src[e]) * OUT_FEAT + q * 4;
    ushort4 u = *(const ushort4*)rp;
    float* op = out + (size_t)dst[e] * OUT_FEAT + q * 4;
    atomicAdd(op + 0, bf2f(u.x) * nv);
    atomicAdd(op + 1, bf2f(u.y) * nv);
    atomicAdd(op + 2, bf2f(u.z) * nv);
    atomicAdd(op + 3, bf2f(u.w) * nv);
}

__global__ __launch_bounds__(256) void k_direct(const float* __restrict__ feat,
                                                const float* __restrict__ W,
                                                const float* __restrict__ norm,
                                                const int* __restrict__ etypes,
                                                const int* __restrict__ src,
                                                const int* __restrict__ dst,
                                                float* __restrict__ out) {
    int gid = blockIdx.x * 256 + threadIdx.x;
    int e = gid >> 4;
    int q = gid & 15;
    if (e >= N_EDGES) return;
    float nv = norm[e];
    const float* fs = feat + (size_t)src[e] * IN_FEAT;
    const float* wp = W + (size_t)etypes[e] * 4096 + q * 4;
    float ax = 0.f, ay = 0.f, az = 0.f, aw = 0.f;
    #pragma unroll 8
    for (int i = 0; i < IN_FEAT; ++i) {
        float f = fs[i];
        float4 w = *(const float4*)(wp + i * OUT_FEAT);
        ax += f * w.x; ay += f * w.y; az += f * w.z; aw += f * w.w;
    }
    float* op = out + (size_t)dst[e] * OUT_FEAT + q * 4;
    atomicAdd(op + 0, ax * nv);
    atomicAdd(op + 1, ay * nv);
    atomicAdd(op + 2, az * nv);
    atomicAdd(op + 3, aw * nv);
}

extern "C" void kernel_launch(void* const* d_in, const int* in_sizes, int n_in,
                              void* d_out, int out_size, void* d_ws, size_t ws_size,
                              hipStream_t stream) {
    const float* feat   = (const float*)d_in[0];
    const float* norm   = (const float*)d_in[1];
    const float* W      = (const float*)d_in[2];
    const int*   etypes = (const int*)d_in[3];
    const int*   src    = (const int*)d_in[4];
    const int*   dst    = (const int*)d_in[5];
    float* out = (float*)d_out;

    const int ntiles = (N_NODES + 63) / 64;    // 1563
    const int nscat  = (N_EDGES * 16) / 256;   // 100000

    // ws layout, 256B-aligned pieces
    const size_t sz_tr    = (size_t)NUM_RELS * N_NODES * OUT_FEAT * 2;          // 102,400,000
    const size_t sz_cnt   = (((size_t)NCHUNK * NB * 4) + 255) & ~(size_t)255;   // ~1.22 MB
    const size_t sz_poff  = (((size_t)NB * PSTR * 4) + 255) & ~(size_t)255;     // ~1.23 MB
    const size_t sz_btot  = 3328;
    const size_t sz_bbase = 3328;
    const size_t sz_pay   = (size_t)N_EDGES * 8;                                 // 12.8 MB

    char* p = (char*)d_ws;
    unsigned short* trb = (unsigned short*)p;  p += sz_tr;
    int*  cnt_kb  = (int*)p;                   p += sz_cnt;
    int*  poff    = (int*)p;                   p += sz_poff;
    int*  btot    = (int*)p;                   p += sz_btot;
    int*  bbase   = (int*)p;                   p += sz_bbase;
    int2* payload = (int2*)p;                  p += sz_pay;
    const size_t need = (size_t)(p - (char*)d_ws);   // ~117.7 MB

    if (ws_size >= need) {
        k_transform  <<<ntiles, 256, 0, stream>>>(feat, W, trb);
        k_bhist      <<<NCHUNK, 256, 0, stream>>>(dst, cnt_kb);
        k_scan_bucket<<<NB,     256, 0, stream>>>(cnt_kb, poff, btot);
        k_scan_tot   <<<1,      256, 0, stream>>>(btot, bbase);
        k_bin        <<<NCHUNK, 256, 0, stream>>>(etypes, src, dst, norm, poff, bbase, payload);
        k_agg        <<<NB,     512, 0, stream>>>(trb, payload, bbase, out);
    } else if (ws_size >= sz_tr) {
        hipMemsetAsync(d_out, 0, (size_t)out_size * sizeof(float), stream);
        k_transform<<<ntiles, 256, 0, stream>>>(feat, W, trb);
        k_scatter<<<nscat, 256, 0, stream>>>(trb, norm, etypes, src, dst, out);
    } else {
        hipMemsetAsync(d_out, 0, (size_t)out_size * sizeof(float), stream);
        k_direct<<<nscat, 256, 0, stream>>>(feat, W, norm, etypes, src, dst, out);
    }
}

// Round 7
// 112.077 us; speedup vs baseline: 7.2254x; 1.6100x over previous
//
#include <hip/hip_runtime.h>
#include <hip/hip_bf16.h>

#define N_NODES 100000
#define N_EDGES 1600000
#define IN_FEAT 64
#define OUT_FEAT 64
#define NUM_RELS 8

#define BSHIFT 7
#define BSZ 128                                   // nodes per bucket
#define NB ((N_NODES + BSZ - 1) / BSZ)            // 782 buckets
#define CHUNK 4096
#define NCHUNK ((N_EDGES + CHUNK - 1) / CHUNK)    // 391 edge chunks
#define PSTR 392                                  // poff row stride
#define MAXBUCK 2944                              // bucket LDS cap (mean 2046, ~20 sigma)

typedef __attribute__((ext_vector_type(8))) short short8;
typedef __attribute__((ext_vector_type(8))) unsigned short ushort8;
typedef __attribute__((ext_vector_type(4))) float f32x4;

// bf16 helpers
static __device__ __forceinline__ unsigned short f2bf(float x) {
    unsigned u = __float_as_uint(x);
    unsigned r = (u + 0x7FFFu + ((u >> 16) & 1u)) >> 16;
    return (unsigned short)r;
}
static __device__ __forceinline__ float bf2f(unsigned short h) {
    return __uint_as_float(((unsigned)h) << 16);
}
static __device__ __forceinline__ float bflo(unsigned v) { return __uint_as_float(v << 16); }
static __device__ __forceinline__ float bfhi(unsigned v) { return __uint_as_float(v & 0xFFFF0000u); }

// ---------------------------------------------------------------------------
// K0: one-time W transpose+cast: Wt[r][o][i] (bf16) = W[r][i][o]. 64KB.
// ---------------------------------------------------------------------------
__global__ __launch_bounds__(256) void k_prep(const float* __restrict__ W,
                                              unsigned short* __restrict__ Wt) {
    __shared__ float Wl[64 * 64];   // [i][o]
    const int r = blockIdx.x, t = threadIdx.x;
    #pragma unroll
    for (int it = 0; it < 16; ++it) {
        int idx = it * 256 + t;
        Wl[idx] = W[(size_t)r * 4096 + idx];
    }
    __syncthreads();
    const int o = t >> 2, iq = t & 3;           // 16 i-values per thread
    unsigned short tmp[16];
    #pragma unroll
    for (int k = 0; k < 16; ++k) tmp[k] = f2bf(Wl[(iq * 16 + k) * 64 + o]);
    ushort8* dst = (ushort8*)(Wt + ((size_t)r * 64 + o) * 64 + iq * 16);
    dst[0] = *(ushort8*)&tmp[0];
    dst[1] = *(ushort8*)&tmp[8];
}

// ---------------------------------------------------------------------------
// K1 (MFMA): tr[r][n][o] (bf16) = sum_i feat[n][i] * W[r][i][o]
// Round-6 f32-VALU version was 109us (floor 42us FMA-bound, 58% VALUBusy,
// 1.4M bank conflicts). MFMA compute is ~3us -> write-bound ~25us.
// Block = 64-node tile, 4 waves; wave w owns rows 16w..16w+15. Per rel:
// stage Wt[r] tile; 2 a-frags (shared over 4 N-tiles) + 8 b-frags + 8
// mfma_f32_16x16x32_bf16. LDS stride 72 bf16 -> 2-way conflicts only (free).
// A-frag: lane holds row=(l&15), k=(l>>4)*8..+7 (+32 for kstep 1).
// C/D (m89-verified): reg j -> row=(l>>4)*4+j, col=l&15.
// ---------------------------------------------------------------------------
__global__ __launch_bounds__(256) void k_transform(const float* __restrict__ feat,
                                                   const unsigned short* __restrict__ Wt,
                                                   unsigned short* __restrict__ trb) {
    __shared__ unsigned short Ft[64 * 72];    // [row][k], pad 72
    __shared__ unsigned short Wtl[64 * 72];   // [col][k], pad 72
    const int tid = threadIdx.x;
    const int n0b = blockIdx.x * 64;
    const int lane = tid & 63, w = tid >> 6;
    const int lr = lane & 15, lg = lane >> 4;   // frag row/col, k-group

    // stage feat tile as bf16 (coalesced float4 reads, ushort4 LDS writes)
    #pragma unroll
    for (int it = 0; it < 4; ++it) {
        int m = it * 256 + tid;
        int row = m >> 4, c4 = m & 15;
        int gn = n0b + row;
        float4 v = make_float4(0.f, 0.f, 0.f, 0.f);
        if (gn < N_NODES) v = *(const float4*)(feat + (size_t)gn * IN_FEAT + c4 * 4);
        ushort4 sv;
        sv.x = f2bf(v.x); sv.y = f2bf(v.y); sv.z = f2bf(v.z); sv.w = f2bf(v.w);
        *(ushort4*)&Ft[row * 72 + c4 * 4] = sv;
    }

    for (int rel = 0; rel < NUM_RELS; ++rel) {
        __syncthreads();   // previous rel's Wtl reads done (also fences Ft stage on rel 0)
        #pragma unroll
        for (int it = 0; it < 2; ++it) {
            int m = it * 256 + tid;            // m in [0,512): 8 ushorts each
            int row = m >> 3, kq = m & 7;
            *(ushort8*)&Wtl[row * 72 + kq * 8] =
                *(const ushort8*)(Wt + (size_t)rel * 4096 + m * 8);
        }
        __syncthreads();

        // a-frags: row = 16w + lr, k = 32*ks + 8*lg
        short8 a0 = *(const short8*)&Ft[(16 * w + lr) * 72 + lg * 8];
        short8 a1 = *(const short8*)&Ft[(16 * w + lr) * 72 + 32 + lg * 8];

        #pragma unroll
        for (int nt = 0; nt < 4; ++nt) {
            short8 b0 = *(const short8*)&Wtl[(nt * 16 + lr) * 72 + lg * 8];
            short8 b1 = *(const short8*)&Wtl[(nt * 16 + lr) * 72 + 32 + lg * 8];
            f32x4 acc = {0.f, 0.f, 0.f, 0.f};
            acc = __builtin_amdgcn_mfma_f32_16x16x32_bf16(a0, b0, acc, 0, 0, 0);
            acc = __builtin_amdgcn_mfma_f32_16x16x32_bf16(a1, b1, acc, 0, 0, 0);
            #pragma unroll
            for (int j = 0; j < 4; ++j) {
                int row = n0b + 16 * w + lg * 4 + j;
                if (row < N_NODES)
                    trb[((size_t)rel * N_NODES + row) * OUT_FEAT + nt * 16 + lr] = f2bf(acc[j]);
            }
        }
    }
}

// ---------------------------------------------------------------------------
// Exclusive block scan over arr[0..1023] (LDS), 256 threads. Returns total.
// ---------------------------------------------------------------------------
__device__ __forceinline__ int block_scan1024(int* arr, int* tmp) {
    const int t = threadIdx.x;
    const int i0 = t * 4;
    int v0 = arr[i0], v1 = arr[i0 + 1], v2 = arr[i0 + 2], v3 = arr[i0 + 3];
    int s = v0 + v1 + v2 + v3;
    tmp[t] = s;
    __syncthreads();
    for (int off = 1; off < 256; off <<= 1) {
        int x = (t >= off) ? tmp[t - off] : 0;
        __syncthreads();
        tmp[t] += x;
        __syncthreads();
    }
    int excl = tmp[t] - s;
    int total = tmp[255];
    arr[i0]     = excl;
    arr[i0 + 1] = excl + v0;
    arr[i0 + 2] = excl + v0 + v1;
    arr[i0 + 3] = excl + v0 + v1 + v2;
    __syncthreads();
    return total;
}

// ---------------------------------------------------------------------------
// S1: per-chunk bucket histogram. cnt_kb[k][b] (coalesced writes).
// ---------------------------------------------------------------------------
__global__ __launch_bounds__(256) void k_bhist(const int* __restrict__ dst,
                                               int* __restrict__ cnt_kb) {
    __shared__ int h[NB];
    const int k = blockIdx.x, t = threadIdx.x;
    for (int i = t; i < NB; i += 256) h[i] = 0;
    __syncthreads();
    const int e0 = k * CHUNK;
    #pragma unroll
    for (int i = 0; i < 16; ++i) {
        int e = e0 + t + i * 256;
        if (e < N_EDGES) atomicAdd(&h[dst[e] >> BSHIFT], 1);
    }
    __syncthreads();
    for (int i = t; i < NB; i += 256) cnt_kb[(size_t)k * NB + i] = h[i];
}

// ---------------------------------------------------------------------------
// S2a: per-bucket prefix over chunks: poff[b][k]; bucket totals -> btot.
// ---------------------------------------------------------------------------
__global__ __launch_bounds__(256) void k_scan_bucket(const int* __restrict__ cnt_kb,
                                                     int* __restrict__ poff,
                                                     int* __restrict__ btot) {
    __shared__ int arr[1024];
    __shared__ int tmp[256];
    const int b = blockIdx.x, t = threadIdx.x;
    for (int i = t; i < 1024; i += 256)
        arr[i] = (i < NCHUNK) ? cnt_kb[(size_t)i * NB + b] : 0;
    __syncthreads();
    int total = block_scan1024(arr, tmp);
    for (int i = t; i < NCHUNK; i += 256) poff[(size_t)b * PSTR + i] = arr[i];
    if (t == 0) btot[b] = total;
}

// ---------------------------------------------------------------------------
// S2b: scan bucket totals -> bbase[0..NB], bbase[NB]=E.
// ---------------------------------------------------------------------------
__global__ __launch_bounds__(256) void k_scan_tot(const int* __restrict__ btot,
                                                  int* __restrict__ bbase) {
    __shared__ int arr[1024];
    __shared__ int tmp[256];
    const int t = threadIdx.x;
    for (int i = t; i < 1024; i += 256) arr[i] = (i < NB) ? btot[i] : 0;
    __syncthreads();
    block_scan1024(arr, tmp);
    for (int i = t; i < NB; i += 256) bbase[i] = arr[i];
    if (t == 0) bbase[NB] = N_EDGES;
}

// ---------------------------------------------------------------------------
// S3: bin edges into bucket-sorted payload with EXACT positions (chunk is
// counting-sorted in LDS, runs copied to piecewise-contiguous global
// positions -> line-dense writes). payload = { rowid | ldst<<20 , norm }.
// ---------------------------------------------------------------------------
__global__ __launch_bounds__(256) void k_bin(const int* __restrict__ etypes,
                                             const int* __restrict__ src,
                                             const int* __restrict__ dst,
                                             const float* __restrict__ norm,
                                             const int* __restrict__ poff,
                                             const int* __restrict__ bbase,
                                             int2* __restrict__ payload) {
    __shared__ int hist[1024];
    __shared__ int tmp[256];
    __shared__ int lcur[NB];
    __shared__ int goff[NB];
    __shared__ int2 ordered[CHUNK];
    __shared__ unsigned short bkt_of[CHUNK];
    const int k = blockIdx.x, t = threadIdx.x;
    const int e0 = k * CHUNK;
    const int cnt = min(CHUNK, N_EDGES - e0);

    for (int i = t; i < 1024; i += 256) hist[i] = 0;
    __syncthreads();
    #pragma unroll
    for (int i = 0; i < 16; ++i) {
        int e = e0 + t + i * 256;
        if (e < N_EDGES) atomicAdd(&hist[dst[e] >> BSHIFT], 1);
    }
    __syncthreads();
    block_scan1024(hist, tmp);           // hist -> local exclusive base
    for (int i = t; i < NB; i += 256) {
        int lb = hist[i];
        lcur[i] = lb;
        goff[i] = bbase[i] + poff[(size_t)i * PSTR + k] - lb;
    }
    __syncthreads();
    #pragma unroll
    for (int i = 0; i < 16; ++i) {
        int e = e0 + t + i * 256;
        if (e < N_EDGES) {
            int d = dst[e];
            int b = d >> BSHIFT;
            int pos = atomicAdd(&lcur[b], 1);
            int rowid = etypes[e] * N_NODES + src[e];
            ordered[pos] = make_int2(rowid | ((d & (BSZ - 1)) << 20), __float_as_int(norm[e]));
            bkt_of[pos] = (unsigned short)b;
        }
    }
    __syncthreads();
    for (int j = t; j < cnt; j += 256) {
        int b = bkt_of[j];
        payload[goff[b] + j] = ordered[j];   // consecutive j -> consecutive g within a run
    }
}

// ---------------------------------------------------------------------------
// S4: block (512 thr) per bucket, atomic-free register accumulation (rounds
// 4/5 both hit a 680us LDS-atomic wall; this structure runs <<100us).
// Stage bucket payload in LDS, counting-sort by node, then 64 8-lane groups
// each own 2 nodes: gather bf16 rows (uint4/lane), accumulate in 8 f32 regs,
// one direct row store per node (zeros for degree-0).
// ---------------------------------------------------------------------------
__global__ __launch_bounds__(512) void k_agg(const unsigned short* __restrict__ trb,
                                             const int2* __restrict__ payload,
                                             const int* __restrict__ bbase,
                                             float* __restrict__ out) {
    __shared__ int2 pseg[MAXBUCK];            // 23,552 B
    __shared__ unsigned short sidx[MAXBUCK];  //  5,888 B
    __shared__ int cnt128[BSZ];
    __shared__ int scan_tmp[BSZ];
    __shared__ int ncur[BSZ];
    __shared__ int nbase[BSZ + 1];
    const int b = blockIdx.x, t = threadIdx.x;

    const int s0 = bbase[b], s1 = bbase[b + 1];
    const int cntb = s1 - s0;
    const int cstage = min(cntb, MAXBUCK);

    if (t < BSZ) cnt128[t] = 0;
    __syncthreads();

    for (int i = t; i < cstage; i += 512) {
        int2 p = payload[s0 + i];
        pseg[i] = p;
        atomicAdd(&cnt128[(p.x >> 20) & 127], 1);
    }
    __syncthreads();

    if (t < BSZ) scan_tmp[t] = cnt128[t];
    __syncthreads();
    for (int off = 1; off < BSZ; off <<= 1) {
        int x = 0;
        if (t < BSZ && t >= off) x = scan_tmp[t - off];
        __syncthreads();
        if (t < BSZ) scan_tmp[t] += x;
        __syncthreads();
    }
    if (t < BSZ) {
        int inc = scan_tmp[t];
        int exc = inc - cnt128[t];
        nbase[t] = exc;
        ncur[t] = exc;
        if (t == BSZ - 1) nbase[BSZ] = inc;
    }
    __syncthreads();

    for (int i = t; i < cstage; i += 512) {
        int ld = (pseg[i].x >> 20) & 127;
        int pos = atomicAdd(&ncur[ld], 1);
        sidx[pos] = (unsigned short)i;
    }
    __syncthreads();

    const int gg = t >> 3;          // group id 0..63
    const int q  = t & 7;           // lane within group
    const int n0g = b << BSHIFT;

    #pragma unroll
    for (int rr = 0; rr < 2; ++rr) {
        int r = gg + rr * 64;
        int j0 = nbase[r], j1 = nbase[r + 1];
        float a0 = 0.f, a1 = 0.f, a2 = 0.f, a3 = 0.f;
        float a4 = 0.f, a5 = 0.f, a6 = 0.f, a7 = 0.f;
        int j = j0;
        for (; j + 1 < j1; j += 2) {
            int2 pa = pseg[sidx[j]];
            int2 pb = pseg[sidx[j + 1]];
            uint4 ua = *(const uint4*)(trb + (size_t)(pa.x & 0xFFFFF) * OUT_FEAT + (q << 3));
            uint4 ub = *(const uint4*)(trb + (size_t)(pb.x & 0xFFFFF) * OUT_FEAT + (q << 3));
            float na = __int_as_float(pa.y);
            float nb_ = __int_as_float(pb.y);
            a0 += bflo(ua.x) * na; a1 += bfhi(ua.x) * na;
            a2 += bflo(ua.y) * na; a3 += bfhi(ua.y) * na;
            a4 += bflo(ua.z) * na; a5 += bfhi(ua.z) * na;
            a6 += bflo(ua.w) * na; a7 += bfhi(ua.w) * na;
            a0 += bflo(ub.x) * nb_; a1 += bfhi(ub.x) * nb_;
            a2 += bflo(ub.y) * nb_; a3 += bfhi(ub.y) * nb_;
            a4 += bflo(ub.z) * nb_; a5 += bfhi(ub.z) * nb_;
            a6 += bflo(ub.w) * nb_; a7 += bfhi(ub.w) * nb_;
        }
        if (j < j1) {
            int2 p = pseg[sidx[j]];
            uint4 u = *(const uint4*)(trb + (size_t)(p.x & 0xFFFFF) * OUT_FEAT + (q << 3));
            float nv = __int_as_float(p.y);
            a0 += bflo(u.x) * nv; a1 += bfhi(u.x) * nv;
            a2 += bflo(u.y) * nv; a3 += bfhi(u.y) * nv;
            a4 += bflo(u.z) * nv; a5 += bfhi(u.z) * nv;
            a6 += bflo(u.w) * nv; a7 += bfhi(u.w) * nv;
        }
        int n = n0g + r;
        if (n < N_NODES) {
            float* op = out + (size_t)n * OUT_FEAT + (q << 3);
            *(float4*)op       = make_float4(a0, a1, a2, a3);
            *(float4*)(op + 4) = make_float4(a4, a5, a6, a7);
        }
    }

    if (cntb > MAXBUCK) {   // ~20-sigma safety path, never taken for this input
        __syncthreads();
        for (int i = MAXBUCK + t; i < cntb; i += 512) {
            int2 p = payload[s0 + i];
            int row = p.x & 0xFFFFF;
            int n = n0g + ((p.x >> 20) & 127);
            float nv = __int_as_float(p.y);
            if (n < N_NODES)
                for (int c = 0; c < OUT_FEAT; ++c)
                    atomicAdd(&out[(size_t)n * OUT_FEAT + c],
                              bf2f(trb[(size_t)row * OUT_FEAT + c]) * nv);
        }
    }
}

// ---------------------------------------------------------------------------
// Fallbacks for small ws.
// ---------------------------------------------------------------------------
__global__ __launch_bounds__(256) void k_scatter(const unsigned short* __restrict__ trb,
                                                 const float* __restrict__ norm,
                                                 const int* __restrict__ etypes,
                                                 const int* __restrict__ src,
                                                 const int* __restrict__ dst,
                                                 float* __restrict__ out) {
    int gid = blockIdx.x * 256 + threadIdx.x;
    int e = gid >> 4;
    int q = gid & 15;
    if (e >= N_EDGES) return;
    float nv = norm[e];
    const unsigned short* rp = trb + ((size_t)etypes[e] * N_NODES + src[e]) * OUT_FEAT + q * 4;
    ushort4 u = *(const ushort4*)rp;
    float* op = out + (size_t)dst[e] * OUT_FEAT + q * 4;
    atomicAdd(op + 0, bf2f(u.x) * nv);
    atomicAdd(op + 1, bf2f(u.y) * nv);
    atomicAdd(op + 2, bf2f(u.z) * nv);
    atomicAdd(op + 3, bf2f(u.w) * nv);
}

__global__ __launch_bounds__(256) void k_direct(const float* __restrict__ feat,
                                                const float* __restrict__ W,
                                                const float* __restrict__ norm,
                                                const int* __restrict__ etypes,
                                                const int* __restrict__ src,
                                                const int* __restrict__ dst,
                                                float* __restrict__ out) {
    int gid = blockIdx.x * 256 + threadIdx.x;
    int e = gid >> 4;
    int q = gid & 15;
    if (e >= N_EDGES) return;
    float nv = norm[e];
    const float* fs = feat + (size_t)src[e] * IN_FEAT;
    const float* wp = W + (size_t)etypes[e] * 4096 + q * 4;
    float ax = 0.f, ay = 0.f, az = 0.f, aw = 0.f;
    #pragma unroll 8
    for (int i = 0; i < IN_FEAT; ++i) {
        float f = fs[i];
        float4 w = *(const float4*)(wp + i * OUT_FEAT);
        ax += f * w.x; ay += f * w.y; az += f * w.z; aw += f * w.w;
    }
    float* op = out + (size_t)dst[e] * OUT_FEAT + q * 4;
    atomicAdd(op + 0, ax * nv);
    atomicAdd(op + 1, ay * nv);
    atomicAdd(op + 2, az * nv);
    atomicAdd(op + 3, aw * nv);
}

extern "C" void kernel_launch(void* const* d_in, const int* in_sizes, int n_in,
                              void* d_out, int out_size, void* d_ws, size_t ws_size,
                              hipStream_t stream) {
    const float* feat   = (const float*)d_in[0];
    const float* norm   = (const float*)d_in[1];
    const float* W      = (const float*)d_in[2];
    const int*   etypes = (const int*)d_in[3];
    const int*   src    = (const int*)d_in[4];
    const int*   dst    = (const int*)d_in[5];
    float* out = (float*)d_out;

    const int ntiles = (N_NODES + 63) / 64;    // 1563
    const int nscat  = (N_EDGES * 16) / 256;   // 100000

    // ws layout, 256B-aligned pieces
    const size_t sz_tr    = (size_t)NUM_RELS * N_NODES * OUT_FEAT * 2;          // 102,400,000
    const size_t sz_wt    = (size_t)NUM_RELS * 64 * 64 * 2;                     // 65,536
    const size_t sz_cnt   = (((size_t)NCHUNK * NB * 4) + 255) & ~(size_t)255;   // ~1.22 MB
    const size_t sz_poff  = (((size_t)NB * PSTR * 4) + 255) & ~(size_t)255;     // ~1.23 MB
    const size_t sz_btot  = 3328;
    const size_t sz_bbase = 3328;
    const size_t sz_pay   = (size_t)N_EDGES * 8;                                 // 12.8 MB

    char* p = (char*)d_ws;
    unsigned short* trb = (unsigned short*)p;  p += sz_tr;
    unsigned short* wt  = (unsigned short*)p;  p += sz_wt;
    int*  cnt_kb  = (int*)p;                   p += sz_cnt;
    int*  poff    = (int*)p;                   p += sz_poff;
    int*  btot    = (int*)p;                   p += sz_btot;
    int*  bbase   = (int*)p;                   p += sz_bbase;
    int2* payload = (int2*)p;                  p += sz_pay;
    const size_t need = (size_t)(p - (char*)d_ws);   // ~117.8 MB

    if (ws_size >= need) {
        k_prep       <<<NUM_RELS, 256, 0, stream>>>(W, wt);
        k_transform  <<<ntiles, 256, 0, stream>>>(feat, wt, trb);
        k_bhist      <<<NCHUNK, 256, 0, stream>>>(dst, cnt_kb);
        k_scan_bucket<<<NB,     256, 0, stream>>>(cnt_kb, poff, btot);
        k_scan_tot   <<<1,      256, 0, stream>>>(btot, bbase);
        k_bin        <<<NCHUNK, 256, 0, stream>>>(etypes, src, dst, norm, poff, bbase, payload);
        k_agg        <<<NB,     512, 0, stream>>>(trb, payload, bbase, out);
    } else if (ws_size >= sz_tr + sz_wt) {
        hipMemsetAsync(d_out, 0, (size_t)out_size * sizeof(float), stream);
        k_prep     <<<NUM_RELS, 256, 0, stream>>>(W, wt);
        k_transform<<<ntiles, 256, 0, stream>>>(feat, wt, trb);
        k_scatter  <<<nscat, 256, 0, stream>>>(trb, norm, etypes, src, dst, out);
    } else {
        hipMemsetAsync(d_out, 0, (size_t)out_size * sizeof(float), stream);
        k_direct<<<nscat, 256, 0, stream>>>(feat, W, norm, etypes, src, dst, out);
    }
}